// Round 5
// baseline (1388.369 us; speedup 1.0000x reference)
//
#include <hip/hip_runtime.h>
#include <hip/hip_fp16.h>
#include <math.h>

#define HN 512   // hidden states
#define HM 4096  // emission symbols
#define HB 64    // batch
#define HT 512   // max seq len

using h2v = decltype(__builtin_amdgcn_cvt_pkrtz(0.f, 0.f));  // __fp16 ext_vector(2)

__device__ __forceinline__ h2v uh2(unsigned int u){ union{unsigned int u; h2v v;} c; c.u=u; return c.v; }
__device__ __forceinline__ h2v pkh2(float a, float b){ return __builtin_amdgcn_cvt_pkrtz(a, b); }
__device__ __forceinline__ unsigned short f16bits(float a){
  union{ h2v v; unsigned int u; } c; c.v = __builtin_amdgcn_cvt_pkrtz(a, a);
  return (unsigned short)(c.u & 0xffffu);
}

__device__ __forceinline__ float dot2(h2v a, h2v b, float c){
#if __has_builtin(__builtin_amdgcn_fdot2)
  return __builtin_amdgcn_fdot2(a, b, c, false);
#else
  return c + (float)a[0]*(float)b[0] + (float)a[1]*(float)b[1];
#endif
}

__device__ __forceinline__ float wsum(float v){
  #pragma unroll
  for(int o=32;o>0;o>>=1) v += __shfl_xor(v,o,64);
  return v;
}
__device__ __forceinline__ float wmax(float v){
  #pragma unroll
  for(int o=32;o>0;o>>=1) v = fmaxf(v,__shfl_xor(v,o,64));
  return v;
}

__device__ __forceinline__ float blockSum512(float v, float* red, float* bc){
  v = wsum(v);
  if((threadIdx.x & 63)==0) red[threadIdx.x>>6] = v;
  __syncthreads();
  if(threadIdx.x < 64){
    float s = (threadIdx.x<8)? red[threadIdx.x] : 0.0f;
    #pragma unroll
    for(int o=4;o>0;o>>=1) s += __shfl_xor(s,o,64);
    if(threadIdx.x==0) *bc = s;
  }
  __syncthreads();
  return *bc;
}
__device__ __forceinline__ float blockMax512(float v, float* red, float* bc){
  v = wmax(v);
  if((threadIdx.x & 63)==0) red[threadIdx.x>>6] = v;
  __syncthreads();
  if(threadIdx.x < 64){
    float s = (threadIdx.x<8)? red[threadIdx.x] : -INFINITY;
    #pragma unroll
    for(int o=4;o>0;o>>=1) s = fmaxf(s, __shfl_xor(s,o,64));
    if(threadIdx.x==0) *bc = s;
  }
  __syncthreads();
  return *bc;
}

__device__ __forceinline__ unsigned short f2bf(float f){
  unsigned int u = __float_as_uint(f);
  unsigned int r = (u + 0x7fffu + ((u>>16)&1u)) >> 16;  // RNE
  return (unsigned short)r;
}
__device__ __forceinline__ float bf2f(unsigned int w){ return __uint_as_float(w<<16); }

__device__ __forceinline__ float f8dec(unsigned int b){
  unsigned e = (b>>3)&15u, m = b&7u;
  float v = e ? ldexpf(8.0f + (float)m, (int)e - 10) : ldexpf((float)m, -9);
  return (b & 0x80u) ? -v : v;
}
template<bool HI>
__device__ __forceinline__ void f8pair(unsigned int dw, float& a, float& b){
#if __has_builtin(__builtin_amdgcn_cvt_pk_f32_fp8)
  auto r = __builtin_amdgcn_cvt_pk_f32_fp8((int)dw, HI);
  a = r[0]; b = r[1];
#else
  unsigned int s = HI ? (dw>>16) : dw;
  a = f8dec(s & 0xffu); b = f8dec((s>>8)&0xffu);
#endif
}
__device__ __forceinline__ unsigned char f8enc(float v){
#if __has_builtin(__builtin_amdgcn_cvt_pk_fp8_f32)
  int p = __builtin_amdgcn_cvt_pk_fp8_f32(v, v, 0, false);
  return (unsigned char)(p & 0xff);
#else
  if(!(v > 0.0f)) return 0;
  if(v >= 448.0f) return 0x7e;
  int e; frexpf(v, &e);
  int E = e + 6;
  if(E <= 0){
    float q = rintf(ldexpf(v, 9));
    return (unsigned char)q;
  }
  float q = rintf(ldexpf(v, 4 - e));
  if(q >= 16.0f){ E++; q = 8.0f; }
  if(E > 15) return 0x7e;
  return (unsigned char)((E<<3) | ((int)q - 8));
#endif
}

// ---------------- prep kernels ----------------

__global__ __launch_bounds__(512) void k_em_lse(const float* __restrict__ em, float* __restrict__ em_lse){
  __shared__ float red[8]; __shared__ float bc;
  int r = blockIdx.x;
  const float* row = em + (size_t)r*HM;
  float mx = -INFINITY;
  for(int i=threadIdx.x;i<HM;i+=512) mx = fmaxf(mx, row[i]);
  mx = blockMax512(mx, red, &bc);
  float s = 0.f;
  for(int i=threadIdx.x;i<HM;i+=512) s += expf(row[i]-mx);
  s = blockSum512(s, red, &bc);
  if(threadIdx.x==0) em_lse[r] = mx + logf(s);
}

__global__ __launch_bounds__(512) void k_pri(const float* __restrict__ pri, float* __restrict__ P, float* __restrict__ pric){
  __shared__ float red[8]; __shared__ float bc;
  int j = threadIdx.x;
  float v = pri[j];
  float mx = blockMax512(v, red, &bc);
  float w = expf(v-mx);
  float s = blockSum512(w, red, &bc);
  P[j] = w;
  if(j==0) *pric = -logf(s);
}

// emT[m][j] = bf16( exp(log_em[j][m]) ), LDS-tiled transpose
__global__ __launch_bounds__(256) void k_em_tab(const float* __restrict__ em, const float* __restrict__ em_lse,
                                                unsigned short* __restrict__ emT){
  __shared__ unsigned short tile[64][66];
  __shared__ float lsl[64];
  int m0 = blockIdx.x*64, j0 = blockIdx.y*64;
  int tx = threadIdx.x & 63, ty = threadIdx.x >> 6;
  if(threadIdx.x < 64) lsl[threadIdx.x] = em_lse[j0 + threadIdx.x];
  __syncthreads();
  #pragma unroll
  for(int r=0;r<16;r++){
    int jl = ty*16 + r;
    float v = em[(size_t)(j0+jl)*HM + m0 + tx];
    tile[jl][tx] = f2bf(expf(v - lsl[jl]));
  }
  __syncthreads();
  #pragma unroll
  for(int r=0;r<16;r++){
    int ml = ty*16 + r;
    emT[(size_t)(m0+ml)*HN + j0 + tx] = tile[tx][ml];
  }
}

// col-softmax of transition, scaled x256; rows j%8<4 -> f16 pairs (register table),
// j%8>=4 -> fp8 e4m3 (LDS table).
__global__ __launch_bounds__(512) void k_tr(const float* __restrict__ tr,
                                            unsigned short* __restrict__ G1,
                                            unsigned char* __restrict__ L8){
  __shared__ float red[8]; __shared__ float bc;
  int k = blockIdx.x, j = threadIdx.x;
  float v = tr[(size_t)j*HN + k];
  float mx = blockMax512(v, red, &bc);
  float wv = expf(v-mx);
  float s = blockSum512(wv, red, &bc);
  float p = 256.0f * (wv / s);
  int w = k>>6, kl = k&63, k2 = kl>>1, l = j>>3, i = j&7;
  if(i < 4){
    G1[((size_t)((w*4+i)*32 + k2)*64 + l)*2 + (kl&1)] = f16bits(p);
  } else {
    L8[((size_t)((w*16) + (i-4)*4 + (kl>>4))*64 + l)*16 + (kl&15)] = f8enc(p);
  }
}

// ---------------- forward recurrence ----------------
// 64 blocks (1/batch), 512 threads. wave w owns k in [64w,64w+64); lane l owns
// outputs j in {8l+i}. i<4 from register f16 Tr (trr[128]), i>=4 from LDS fp8 Tr.
// amdgpu_waves_per_eu(1,2): VGPR budget 256 so trr stays in registers — the
// launch_bounds min-waves hint alone was ignored (VGPR stayed 116, trr spilled,
// 7.4 GB/launch scratch reload traffic). LDS (147 KB) forces 1 block/CU anyway.
__global__ __launch_bounds__(512) __attribute__((amdgpu_waves_per_eu(1, 2)))
void k_fwd(const int* __restrict__ x, const int* __restrict__ Tl,
           const unsigned short* __restrict__ emTu,
           const float* __restrict__ P, const float* __restrict__ pric,
           const unsigned int* __restrict__ G1u,
           const uint4* __restrict__ Lfp8,
           float* __restrict__ out){
  extern __shared__ char smem[];
  // ah 1024 | red2 64 | xls 2048 | red 16384 | trl 131072  = 150592 B
  uint4*  ah4  = (uint4*)smem;
  unsigned short* ah16 = (unsigned short*)smem;
  float*  red2 = (float*)(smem + 1024);
  int*    xls  = (int*)(smem + 1088);
  float*  red  = (float*)(smem + 3136);
  uint4*  trl  = (uint4*)(smem + 19520);

  const int t = threadIdx.x, w = t>>6, l = t&63, b = blockIdx.x;

  xls[t] = x[b*HT + t];
  for(int i=t;i<8192;i+=512) trl[i] = Lfp8[i];

  unsigned int trr[128];
  #pragma unroll
  for(int r=0;r<128;r++) trr[r] = G1u[(w*128 + r)*64 + l];

  int Tb = Tl[b];
  __syncthreads();

  // ---- t = 0 ----
  int   m  = xls[0];
  float e  = bf2f((unsigned)emTu[(size_t)m*HN + t]);
  float nu = e * P[t];
  {
    float vs = wsum(nu);
    if(l==0) red2[w] = vs;
  }
  __syncthreads();
  float4 r0 = ((float4*)red2)[0], r1 = ((float4*)red2)[1];
  float S = ((r0.x+r0.y)+(r0.z+r0.w))+((r1.x+r1.y)+(r1.z+r1.w));
  float c = pric[0] + __logf(S);
  float sc = 256.0f / S;
  ah16[t] = f16bits(nu * sc);     // wave-local: wave w's slice written by wave w
  int   mn = xls[(Tb>1)?1:0];
  float en = bf2f((unsigned)emTu[(size_t)mn*HN + t]);

  for(int tt=1; tt<Tb; tt++){
    e = en;
    int tnx = (tt+1 < HT)? tt+1 : HT-1;
    mn = xls[tnx];
    en = bf2f((unsigned)emTu[(size_t)mn*HN + t]);    // prefetch next step

    // ---- Phase A: partials over this wave's k-range ----
    unsigned int apk[32];
    {
      uint4* ap4 = (uint4*)apk;
      #pragma unroll
      for(int q=0;q<8;q++) ap4[q] = ah4[8*w + q];
    }
    float acc[8];
    #pragma unroll
    for(int i=0;i<8;i++) acc[i] = 0.0f;

    #pragma unroll
    for(int i=0;i<4;i++){
      #pragma unroll
      for(int k2=0;k2<32;k2++){
        acc[i] = dot2(uh2(trr[i*32+k2]), uh2(apk[k2]), acc[i]);
      }
    }
    #pragma unroll
    for(int i5=0;i5<4;i5++){
      #pragma unroll
      for(int q=0;q<4;q++){
        uint4 F = trl[(w*16 + i5*4 + q)*64 + l];
        unsigned int dws[4] = {F.x, F.y, F.z, F.w};
        #pragma unroll
        for(int d=0; d<4; d++){
          int k2b = 8*q + 2*d;
          float fa, fb;
          f8pair<false>(dws[d], fa, fb);
          acc[4+i5] = dot2(pkh2(fa,fb), uh2(apk[k2b]), acc[4+i5]);
          f8pair<true>(dws[d], fa, fb);
          acc[4+i5] = dot2(pkh2(fa,fb), uh2(apk[k2b+1]), acc[4+i5]);
        }
      }
    }
    // swizzled partial store: output j=8l+i from wave w at red[i*512 + w*64 + (l^(8i))]
    #pragma unroll
    for(int i=0;i<8;i++) red[i*512 + w*64 + (l ^ (i<<3))] = acc[i];
    __syncthreads();                       // B1

    // ---- Phase B: thread t finalizes output j = t ----
    {
      int lo = t>>3, ii = t&7;
      float v = 0.f;
      #pragma unroll
      for(int ww=0;ww<8;ww++) v += red[ii*512 + ww*64 + (lo ^ (ii<<3))];
      v *= (1.0f/65536.0f);
      nu = v * e;
    }
    {
      float vs = wsum(nu);
      if(l==0) red2[w] = vs;
    }
    __syncthreads();                       // B2
    float4 q0 = ((float4*)red2)[0], q1 = ((float4*)red2)[1];
    S = ((q0.x+q0.y)+(q0.z+q0.w))+((q1.x+q1.y)+(q1.z+q1.w));
    c += __logf(S);
    sc = 256.0f / S;
    ah16[t] = f16bits(nu * sc);            // own-wave consumption next iter; B2-protected vs red
  }
  if(t==0) out[b] = c;
}

extern "C" void kernel_launch(void* const* d_in, const int* in_sizes, int n_in,
                              void* d_out, int out_size, void* d_ws, size_t ws_size,
                              hipStream_t stream){
  const int*   x   = (const int*)d_in[0];
  const int*   T   = (const int*)d_in[1];
  const float* em  = (const float*)d_in[2];
  const float* tr  = (const float*)d_in[3];
  const float* pri = (const float*)d_in[4];
  float* out = (float*)d_out;

  char* ws = (char*)d_ws;
  float* em_lse = (float*)ws;                                   // 2 KiB
  float* P      = (float*)(ws + 2048);                          // 2 KiB
  float* pric   = (float*)(ws + 4096);                          // 16 B
  unsigned short* emT = (unsigned short*)(ws + 24576);          // 4 MiB
  unsigned short* G1  = (unsigned short*)(ws + 24576 + (size_t)HM*HN*2);           // 256 KiB
  unsigned char*  L8  = (unsigned char*)(ws + 24576 + (size_t)HM*HN*2 + 262144);   // 128 KiB

  k_em_lse<<<HN, 512, 0, stream>>>(em, em_lse);
  k_pri  <<<1,  512, 0, stream>>>(pri, P, pric);
  k_tr   <<<HN, 512, 0, stream>>>(tr, G1, L8);
  k_em_tab<<<dim3(HM/64, HN/64), 256, 0, stream>>>(em, em_lse, emT);

  const int lds_bytes = 19520 + 131072;   // 150592
  (void)hipFuncSetAttribute((const void*)k_fwd, hipFuncAttributeMaxDynamicSharedMemorySize, lds_bytes);
  k_fwd  <<<HB, 512, lds_bytes, stream>>>(x, T, emT, P, pric,
                                          (const unsigned int*)G1, (const uint4*)L8, out);
}

// Round 6
// 1384.193 us; speedup vs baseline: 1.0030x; 1.0030x over previous
//
#include <hip/hip_runtime.h>
#include <hip/hip_fp16.h>
#include <math.h>

#define HN 512   // hidden states
#define HM 4096  // emission symbols
#define HB 64    // batch
#define HT 512   // max seq len

using h2v = decltype(__builtin_amdgcn_cvt_pkrtz(0.f, 0.f));  // __fp16 ext_vector(2)

__device__ __forceinline__ h2v uh2(unsigned int u){ union{unsigned int u; h2v v;} c; c.u=u; return c.v; }
__device__ __forceinline__ h2v pkh2(float a, float b){ return __builtin_amdgcn_cvt_pkrtz(a, b); }
__device__ __forceinline__ unsigned short f16bits(float a){
  union{ h2v v; unsigned int u; } c; c.v = __builtin_amdgcn_cvt_pkrtz(a, a);
  return (unsigned short)(c.u & 0xffffu);
}

__device__ __forceinline__ float dot2(h2v a, h2v b, float c){
#if __has_builtin(__builtin_amdgcn_fdot2)
  return __builtin_amdgcn_fdot2(a, b, c, false);
#else
  return c + (float)a[0]*(float)b[0] + (float)a[1]*(float)b[1];
#endif
}

__device__ __forceinline__ float wsum(float v){
  #pragma unroll
  for(int o=32;o>0;o>>=1) v += __shfl_xor(v,o,64);
  return v;
}
__device__ __forceinline__ float wmax(float v){
  #pragma unroll
  for(int o=32;o>0;o>>=1) v = fmaxf(v,__shfl_xor(v,o,64));
  return v;
}

__device__ __forceinline__ float blockSum512(float v, float* red, float* bc){
  v = wsum(v);
  if((threadIdx.x & 63)==0) red[threadIdx.x>>6] = v;
  __syncthreads();
  if(threadIdx.x < 64){
    float s = (threadIdx.x<8)? red[threadIdx.x] : 0.0f;
    #pragma unroll
    for(int o=4;o>0;o>>=1) s += __shfl_xor(s,o,64);
    if(threadIdx.x==0) *bc = s;
  }
  __syncthreads();
  return *bc;
}
__device__ __forceinline__ float blockMax512(float v, float* red, float* bc){
  v = wmax(v);
  if((threadIdx.x & 63)==0) red[threadIdx.x>>6] = v;
  __syncthreads();
  if(threadIdx.x < 64){
    float s = (threadIdx.x<8)? red[threadIdx.x] : -INFINITY;
    #pragma unroll
    for(int o=4;o>0;o>>=1) s = fmaxf(s, __shfl_xor(s,o,64));
    if(threadIdx.x==0) *bc = s;
  }
  __syncthreads();
  return *bc;
}

__device__ __forceinline__ unsigned short f2bf(float f){
  unsigned int u = __float_as_uint(f);
  unsigned int r = (u + 0x7fffu + ((u>>16)&1u)) >> 16;  // RNE
  return (unsigned short)r;
}
__device__ __forceinline__ float bf2f(unsigned int w){ return __uint_as_float(w<<16); }

__device__ __forceinline__ float f8dec(unsigned int b){
  unsigned e = (b>>3)&15u, m = b&7u;
  float v = e ? ldexpf(8.0f + (float)m, (int)e - 10) : ldexpf((float)m, -9);
  return (b & 0x80u) ? -v : v;
}
template<bool HI>
__device__ __forceinline__ void f8pair(unsigned int dw, float& a, float& b){
#if __has_builtin(__builtin_amdgcn_cvt_pk_f32_fp8)
  auto r = __builtin_amdgcn_cvt_pk_f32_fp8((int)dw, HI);
  a = r[0]; b = r[1];
#else
  unsigned int s = HI ? (dw>>16) : dw;
  a = f8dec(s & 0xffu); b = f8dec((s>>8)&0xffu);
#endif
}
__device__ __forceinline__ unsigned char f8enc(float v){
#if __has_builtin(__builtin_amdgcn_cvt_pk_fp8_f32)
  int p = __builtin_amdgcn_cvt_pk_fp8_f32(v, v, 0, false);
  return (unsigned char)(p & 0xff);
#else
  if(!(v > 0.0f)) return 0;
  if(v >= 448.0f) return 0x7e;
  int e; frexpf(v, &e);
  int E = e + 6;
  if(E <= 0){
    float q = rintf(ldexpf(v, 9));
    return (unsigned char)q;
  }
  float q = rintf(ldexpf(v, 4 - e));
  if(q >= 16.0f){ E++; q = 8.0f; }
  if(E > 15) return 0x7e;
  return (unsigned char)((E<<3) | ((int)q - 8));
#endif
}

// ---------------- prep kernels ----------------

__global__ __launch_bounds__(512) void k_em_lse(const float* __restrict__ em, float* __restrict__ em_lse){
  __shared__ float red[8]; __shared__ float bc;
  int r = blockIdx.x;
  const float* row = em + (size_t)r*HM;
  float mx = -INFINITY;
  for(int i=threadIdx.x;i<HM;i+=512) mx = fmaxf(mx, row[i]);
  mx = blockMax512(mx, red, &bc);
  float s = 0.f;
  for(int i=threadIdx.x;i<HM;i+=512) s += expf(row[i]-mx);
  s = blockSum512(s, red, &bc);
  if(threadIdx.x==0) em_lse[r] = mx + logf(s);
}

__global__ __launch_bounds__(512) void k_pri(const float* __restrict__ pri, float* __restrict__ P, float* __restrict__ pric){
  __shared__ float red[8]; __shared__ float bc;
  int j = threadIdx.x;
  float v = pri[j];
  float mx = blockMax512(v, red, &bc);
  float w = expf(v-mx);
  float s = blockSum512(w, red, &bc);
  P[j] = w;
  if(j==0) *pric = -logf(s);
}

// emT[m][j] = bf16( exp(log_em[j][m]) ), LDS-tiled transpose
__global__ __launch_bounds__(256) void k_em_tab(const float* __restrict__ em, const float* __restrict__ em_lse,
                                                unsigned short* __restrict__ emT){
  __shared__ unsigned short tile[64][66];
  __shared__ float lsl[64];
  int m0 = blockIdx.x*64, j0 = blockIdx.y*64;
  int tx = threadIdx.x & 63, ty = threadIdx.x >> 6;
  if(threadIdx.x < 64) lsl[threadIdx.x] = em_lse[j0 + threadIdx.x];
  __syncthreads();
  #pragma unroll
  for(int r=0;r<16;r++){
    int jl = ty*16 + r;
    float v = em[(size_t)(j0+jl)*HM + m0 + tx];
    tile[jl][tx] = f2bf(expf(v - lsl[jl]));
  }
  __syncthreads();
  #pragma unroll
  for(int r=0;r<16;r++){
    int ml = ty*16 + r;
    emT[(size_t)(m0+ml)*HN + j0 + tx] = tile[tx][ml];
  }
}

// col-softmax of transition, scaled x256; rows j%8<4 -> f16 pairs (register table),
// j%8>=4 -> fp8 e4m3 (LDS table).
__global__ __launch_bounds__(512) void k_tr(const float* __restrict__ tr,
                                            unsigned short* __restrict__ G1,
                                            unsigned char* __restrict__ L8){
  __shared__ float red[8]; __shared__ float bc;
  int k = blockIdx.x, j = threadIdx.x;
  float v = tr[(size_t)j*HN + k];
  float mx = blockMax512(v, red, &bc);
  float wv = expf(v-mx);
  float s = blockSum512(wv, red, &bc);
  float p = 256.0f * (wv / s);
  int w = k>>6, kl = k&63, k2 = kl>>1, l = j>>3, i = j&7;
  if(i < 4){
    G1[((size_t)((w*4+i)*32 + k2)*64 + l)*2 + (kl&1)] = f16bits(p);
  } else {
    L8[((size_t)((w*16) + (i-4)*4 + (kl>>4))*64 + l)*16 + (kl&15)] = f8enc(p);
  }
}

// ---------------- forward recurrence ----------------
// 64 blocks (1/batch), 512 threads. wave w owns k in [64w,64w+64); lane l owns
// outputs j in {8l+i}. i<4 from register f16 Tr (trr[128]), i>=4 from LDS fp8 Tr.
// trr is pinned in VGPRs via empty inline-asm ("+v"): rounds 3-5 showed the
// compiler SINKS the 128 G1 loads into the K-loop (VGPR stuck at 116, ~256 KB/CU/step
// refetched from L2, dur frozen at ~1.3 ms). The asm makes each value an opaque
// register def that cannot be rematerialized from memory.
__global__ __launch_bounds__(512) __attribute__((amdgpu_waves_per_eu(1, 2)))
void k_fwd(const int* __restrict__ x, const int* __restrict__ Tl,
           const unsigned short* __restrict__ emTu,
           const float* __restrict__ P, const float* __restrict__ pric,
           const unsigned int* __restrict__ G1u,
           const uint4* __restrict__ Lfp8,
           float* __restrict__ out){
  extern __shared__ char smem[];
  // ah 1024 | red2 64 | xls 2048 | red 16384 | trl 131072  = 150592 B
  uint4*  ah4  = (uint4*)smem;
  unsigned short* ah16 = (unsigned short*)smem;
  float*  red2 = (float*)(smem + 1024);
  int*    xls  = (int*)(smem + 1088);
  float*  red  = (float*)(smem + 3136);
  uint4*  trl  = (uint4*)(smem + 19520);

  const int t = threadIdx.x, w = t>>6, l = t&63, b = blockIdx.x;

  xls[t] = x[b*HT + t];
  for(int i=t;i<8192;i+=512) trl[i] = Lfp8[i];

  unsigned int trr[128];
  #pragma unroll
  for(int r=0;r<128;r++) trr[r] = G1u[(w*128 + r)*64 + l];
  // pin: each trr[r] becomes an opaque asm-defined register value — cannot be
  // sunk into the loop or rematerialized from G1u.
  #pragma unroll
  for(int r=0;r<128;r++) asm volatile("" : "+v"(trr[r]));

  int Tb = Tl[b];
  __syncthreads();

  // ---- t = 0 ----
  int   m  = xls[0];
  float e  = bf2f((unsigned)emTu[(size_t)m*HN + t]);
  float nu = e * P[t];
  {
    float vs = wsum(nu);
    if(l==0) red2[w] = vs;
  }
  __syncthreads();
  float4 r0 = ((float4*)red2)[0], r1 = ((float4*)red2)[1];
  float S = ((r0.x+r0.y)+(r0.z+r0.w))+((r1.x+r1.y)+(r1.z+r1.w));
  float c = pric[0] + __logf(S);
  float sc = 256.0f / S;
  ah16[t] = f16bits(nu * sc);     // wave-local: wave w's slice written by wave w
  int   mn = xls[(Tb>1)?1:0];
  float en = bf2f((unsigned)emTu[(size_t)mn*HN + t]);

  for(int tt=1; tt<Tb; tt++){
    e = en;
    int tnx = (tt+1 < HT)? tt+1 : HT-1;
    mn = xls[tnx];
    en = bf2f((unsigned)emTu[(size_t)mn*HN + t]);    // prefetch next step

    // ---- Phase A: partials over this wave's k-range ----
    unsigned int apk[32];
    {
      uint4* ap4 = (uint4*)apk;
      #pragma unroll
      for(int q=0;q<8;q++) ap4[q] = ah4[8*w + q];
    }
    float acc[8];
    #pragma unroll
    for(int i=0;i<8;i++) acc[i] = 0.0f;

    #pragma unroll
    for(int i=0;i<4;i++){
      #pragma unroll
      for(int k2=0;k2<32;k2++){
        acc[i] = dot2(uh2(trr[i*32+k2]), uh2(apk[k2]), acc[i]);
      }
    }
    #pragma unroll
    for(int i5=0;i5<4;i5++){
      #pragma unroll
      for(int q=0;q<4;q++){
        uint4 F = trl[(w*16 + i5*4 + q)*64 + l];
        unsigned int dws[4] = {F.x, F.y, F.z, F.w};
        #pragma unroll
        for(int d=0; d<4; d++){
          int k2b = 8*q + 2*d;
          float fa, fb;
          f8pair<false>(dws[d], fa, fb);
          acc[4+i5] = dot2(pkh2(fa,fb), uh2(apk[k2b]), acc[4+i5]);
          f8pair<true>(dws[d], fa, fb);
          acc[4+i5] = dot2(pkh2(fa,fb), uh2(apk[k2b+1]), acc[4+i5]);
        }
      }
    }
    // swizzled partial store: output j=8l+i from wave w at red[i*512 + w*64 + (l^(8i))]
    #pragma unroll
    for(int i=0;i<8;i++) red[i*512 + w*64 + (l ^ (i<<3))] = acc[i];
    __syncthreads();                       // B1

    // ---- Phase B: thread t finalizes output j = t ----
    {
      int lo = t>>3, ii = t&7;
      float v = 0.f;
      #pragma unroll
      for(int ww=0;ww<8;ww++) v += red[ii*512 + ww*64 + (lo ^ (ii<<3))];
      v *= (1.0f/65536.0f);
      nu = v * e;
    }
    {
      float vs = wsum(nu);
      if(l==0) red2[w] = vs;
    }
    __syncthreads();                       // B2
    float4 q0 = ((float4*)red2)[0], q1 = ((float4*)red2)[1];
    S = ((q0.x+q0.y)+(q0.z+q0.w))+((q1.x+q1.y)+(q1.z+q1.w));
    c += __logf(S);
    sc = 256.0f / S;
    ah16[t] = f16bits(nu * sc);            // own-wave consumption next iter; B2-protected vs red
  }
  if(t==0) out[b] = c;
}

extern "C" void kernel_launch(void* const* d_in, const int* in_sizes, int n_in,
                              void* d_out, int out_size, void* d_ws, size_t ws_size,
                              hipStream_t stream){
  const int*   x   = (const int*)d_in[0];
  const int*   T   = (const int*)d_in[1];
  const float* em  = (const float*)d_in[2];
  const float* tr  = (const float*)d_in[3];
  const float* pri = (const float*)d_in[4];
  float* out = (float*)d_out;

  char* ws = (char*)d_ws;
  float* em_lse = (float*)ws;                                   // 2 KiB
  float* P      = (float*)(ws + 2048);                          // 2 KiB
  float* pric   = (float*)(ws + 4096);                          // 16 B
  unsigned short* emT = (unsigned short*)(ws + 24576);          // 4 MiB
  unsigned short* G1  = (unsigned short*)(ws + 24576 + (size_t)HM*HN*2);           // 256 KiB
  unsigned char*  L8  = (unsigned char*)(ws + 24576 + (size_t)HM*HN*2 + 262144);   // 128 KiB

  k_em_lse<<<HN, 512, 0, stream>>>(em, em_lse);
  k_pri  <<<1,  512, 0, stream>>>(pri, P, pric);
  k_tr   <<<HN, 512, 0, stream>>>(tr, G1, L8);
  k_em_tab<<<dim3(HM/64, HN/64), 256, 0, stream>>>(em, em_lse, emT);

  const int lds_bytes = 19520 + 131072;   // 150592
  (void)hipFuncSetAttribute((const void*)k_fwd, hipFuncAttributeMaxDynamicSharedMemorySize, lds_bytes);
  k_fwd  <<<HB, 512, lds_bytes, stream>>>(x, T, emT, P, pric,
                                          (const unsigned int*)G1, (const uint4*)L8, out);
}